// Round 1
// baseline (2223.864 us; speedup 1.0000x reference)
//
#include <hip/hip_runtime.h>
#include <cstddef>

#define B 128
#define R 1024

__device__ __forceinline__ float sigf(float x) { return 1.0f / (1.0f + __expf(-x)); }

// ---------------------------------------------------------------------------
// Generic fp32 GEMM: C[m,n] = sum_k A[m,k] * W[n,k] (+bias[n]) (+C) , act
// A: (M,K) row-major w/ lda; W: (N,K) row-major (ld = K); C: ldc.
// M,N divisible by 64; K divisible by 16. grid = (N/64, M/64), block = 256.
// ---------------------------------------------------------------------------
__global__ __launch_bounds__(256) void gemm_kernel(
    const float* __restrict__ A, int lda,
    const float* __restrict__ W,
    const float* __restrict__ bias,
    float* __restrict__ C, int ldc,
    int K, int addC, int act)
{
    __shared__ float As[16][64];
    __shared__ float Bs[16][64];
    const int bm = blockIdx.y * 64;
    const int bn = blockIdx.x * 64;
    const int tid = threadIdx.x;
    const int lr = tid >> 2;          // 0..63
    const int lc = (tid & 3) * 4;     // 0,4,8,12
    const int ty = tid >> 4;          // 0..15
    const int tx = tid & 15;          // 0..15
    float acc[4][4] = {};
    for (int k0 = 0; k0 < K; k0 += 16) {
        float4 a4 = *(const float4*)(A + (size_t)(bm + lr) * lda + k0 + lc);
        float4 b4 = *(const float4*)(W + (size_t)(bn + lr) * K + k0 + lc);
        __syncthreads();
        As[lc + 0][lr] = a4.x; As[lc + 1][lr] = a4.y; As[lc + 2][lr] = a4.z; As[lc + 3][lr] = a4.w;
        Bs[lc + 0][lr] = b4.x; Bs[lc + 1][lr] = b4.y; Bs[lc + 2][lr] = b4.z; Bs[lc + 3][lr] = b4.w;
        __syncthreads();
#pragma unroll
        for (int k = 0; k < 16; ++k) {
            float4 av = *(const float4*)&As[k][ty * 4];
            float4 bv = *(const float4*)&Bs[k][tx * 4];
            float am[4] = {av.x, av.y, av.z, av.w};
            float bb[4] = {bv.x, bv.y, bv.z, bv.w};
#pragma unroll
            for (int i = 0; i < 4; ++i)
#pragma unroll
                for (int j = 0; j < 4; ++j)
                    acc[i][j] = fmaf(am[i], bb[j], acc[i][j]);
        }
    }
#pragma unroll
    for (int i = 0; i < 4; ++i) {
        int row = bm + ty * 4 + i;
#pragma unroll
        for (int j = 0; j < 4; ++j) {
            int col = bn + tx * 4 + j;
            float v = acc[i][j];
            if (bias) v += bias[col];
            if (addC) v += C[(size_t)row * ldc + col];
            if (act == 1) v = fmaxf(v, 0.0f);
            else if (act == 2) v = tanhf(v);
            C[(size_t)row * ldc + col] = v;
        }
    }
}

// ---------------------------------------------------------------------------
// Fused cfe GEMM + tanh + dot(ada_w) + row-reduce into e[b*197 + 1 + s].
// P: (25088,512) p_obj_feats; W: (1024,512) cfe_w. M=25088, N=1024, K=512.
// ---------------------------------------------------------------------------
__global__ __launch_bounds__(256) void cfe_e_kernel(
    const float* __restrict__ P,
    const float* __restrict__ W,
    const float* __restrict__ cb,
    const float* __restrict__ hoe,   // (128,1024) ho_embed
    const float* __restrict__ aw,    // (1024) ada_alpha_w[0]
    float* __restrict__ e)           // (128,197) accumulated
{
    __shared__ float As[16][64];
    __shared__ float Bs[16][64];
    const int bm = blockIdx.y * 64;
    const int bn = blockIdx.x * 64;
    const int tid = threadIdx.x;
    const int lr = tid >> 2;
    const int lc = (tid & 3) * 4;
    const int ty = tid >> 4;
    const int tx = tid & 15;
    float acc[4][4] = {};
    for (int k0 = 0; k0 < 512; k0 += 16) {
        float4 a4 = *(const float4*)(P + (size_t)(bm + lr) * 512 + k0 + lc);
        float4 b4 = *(const float4*)(W + (size_t)(bn + lr) * 512 + k0 + lc);
        __syncthreads();
        As[lc + 0][lr] = a4.x; As[lc + 1][lr] = a4.y; As[lc + 2][lr] = a4.z; As[lc + 3][lr] = a4.w;
        Bs[lc + 0][lr] = b4.x; Bs[lc + 1][lr] = b4.y; Bs[lc + 2][lr] = b4.z; Bs[lc + 3][lr] = b4.w;
        __syncthreads();
#pragma unroll
        for (int k = 0; k < 16; ++k) {
            float4 av = *(const float4*)&As[k][ty * 4];
            float4 bv = *(const float4*)&Bs[k][tx * 4];
            float am[4] = {av.x, av.y, av.z, av.w};
            float bb[4] = {bv.x, bv.y, bv.z, bv.w};
#pragma unroll
            for (int i = 0; i < 4; ++i)
#pragma unroll
                for (int j = 0; j < 4; ++j)
                    acc[i][j] = fmaf(am[i], bb[j], acc[i][j]);
        }
    }
    __shared__ float red[64][17];
#pragma unroll
    for (int i = 0; i < 4; ++i) {
        int m = bm + ty * 4 + i;
        int b = m / 196;
        float part = 0.0f;
#pragma unroll
        for (int j = 0; j < 4; ++j) {
            int n = bn + tx * 4 + j;
            part += tanhf(acc[i][j] + cb[n] + hoe[(size_t)b * R + n]) * aw[n];
        }
        red[ty * 4 + i][tx] = part;
    }
    __syncthreads();
    if (tid < 64) {
        float s = 0.0f;
#pragma unroll
        for (int t = 0; t < 16; ++t) s += red[tid][t];
        int m = bm + tid;
        atomicAdd(&e[(m / 196) * 197 + 1 + (m % 196)], s);
    }
}

// e[b,s] = sum_a tanh(p[b,s,a] + ah[b,a]) * aw[a]   (one wave per (b,s))
__global__ __launch_bounds__(256) void att_e_kernel(
    const float* __restrict__ p, const float* __restrict__ ah,
    const float* __restrict__ aw, float* __restrict__ e, int S)
{
    int wid = threadIdx.x >> 6, lane = threadIdx.x & 63;
    int idx = blockIdx.x * 4 + wid;   // b*S + s
    int b = idx / S;
    const float* pr = p + (size_t)idx * 512;
    const float* ab = ah + (size_t)b * 512;
    float sum = 0.0f;
#pragma unroll
    for (int k = 0; k < 8; ++k) {
        int a = k * 64 + lane;
        sum += tanhf(pr[a] + ab[a]) * aw[a];
    }
#pragma unroll
    for (int off = 32; off; off >>= 1) sum += __shfl_down(sum, off);
    if (lane == 0) e[idx] = sum;
}

// softmax over S (<=256) per row b, optional mask, renormalize. in-place.
__global__ __launch_bounds__(256) void softmax_kernel(
    float* __restrict__ e, const float* __restrict__ mask, int S)
{
    __shared__ float red[256];
    int b = blockIdx.x, tid = threadIdx.x;
    float v = (tid < S) ? e[(size_t)b * S + tid] : -3.4e38f;
    red[tid] = v; __syncthreads();
    for (int s = 128; s; s >>= 1) { if (tid < s) red[tid] = fmaxf(red[tid], red[tid + s]); __syncthreads(); }
    float m = red[0]; __syncthreads();
    float p = (tid < S) ? __expf(v - m) : 0.0f;
    red[tid] = p; __syncthreads();
    for (int s = 128; s; s >>= 1) { if (tid < s) red[tid] += red[tid + s]; __syncthreads(); }
    float s1 = red[0]; __syncthreads();
    float w = p / s1;
    if (mask && tid < S) w *= mask[(size_t)b * S + tid];
    red[tid] = (tid < S) ? w : 0.0f; __syncthreads();
    for (int s = 128; s; s >>= 1) { if (tid < s) red[tid] += red[tid + s]; __syncthreads(); }
    float s2 = red[0];
    if (tid < S) e[(size_t)b * S + tid] = w / s2;
}

// out[b, d] = sum_s w[b,s] * feats[b,s,d]   grid = B*4 blocks x 256 threads
__global__ __launch_bounds__(256) void wsum_kernel(
    const float* __restrict__ w, const float* __restrict__ feats,
    float* __restrict__ out, int ldo, int S)
{
    int idx = blockIdx.x * 256 + threadIdx.x;
    int b = idx >> 10, d = idx & 1023;
    const float* f = feats + ((size_t)b * S) * R + d;
    const float* wb = w + (size_t)b * S;
    float acc = 0.0f;
    for (int s = 0; s < S; ++s) acc = fmaf(wb[s], f[(size_t)s * R], acc);
    out[(size_t)b * ldo + d] = acc;
}

__global__ __launch_bounds__(256) void lstm_kernel(
    const float* __restrict__ g, const float* __restrict__ cprev,
    float* __restrict__ h, float* __restrict__ c)
{
    int idx = blockIdx.x * 256 + threadIdx.x;  // b*1024 + d
    int b = idx >> 10, d = idx & 1023;
    const float* gr = g + (size_t)b * 4096;
    float iv = sigf(gr[d]);
    float fv = sigf(gr[1024 + d]);
    float gv = tanhf(gr[2048 + d]);
    float ov = sigf(gr[3072 + d]);
    float c2 = fv * cprev[idx] + iv * gv;
    c[idx] = c2;
    h[idx] = ov * tanhf(c2);
}

// st = sigmoid(n5) * tanh(c_lang)
__global__ __launch_bounds__(256) void st_kernel(
    const float* __restrict__ n5, const float* __restrict__ clang, float* __restrict__ st)
{
    int idx = blockIdx.x * 256 + threadIdx.x;
    st[idx] = sigf(n5[idx]) * tanhf(clang[idx]);
}

// e[b*197] = sum_r tanh(fre[b,r]+hoe[b,r])*aw[r]  (one wave per b)
__global__ __launch_bounds__(256) void ada_e0_kernel(
    const float* __restrict__ fre, const float* __restrict__ hoe,
    const float* __restrict__ aw, float* __restrict__ e)
{
    int wid = threadIdx.x >> 6, lane = threadIdx.x & 63;
    int b = blockIdx.x * 4 + wid;
    float sum = 0.0f;
#pragma unroll
    for (int k = 0; k < 16; ++k) {
        int r = k * 64 + lane;
        sum += tanhf(fre[(size_t)b * R + r] + hoe[(size_t)b * R + r]) * aw[r];
    }
#pragma unroll
    for (int off = 32; off; off >>= 1) sum += __shfl_down(sum, off);
    if (lane == 0) e[b * 197] = sum;
}

// c_t_hat into huu_in[:, 2048:3072]
__global__ __launch_bounds__(256) void ct_kernel(
    const float* __restrict__ PI, const float* __restrict__ fr,
    const float* __restrict__ attf, float* __restrict__ huu_in)
{
    int idx = blockIdx.x * 256 + threadIdx.x;
    int b = idx >> 10, d = idx & 1023;
    float f = fr[idx];
    const float* pb = PI + b * 197;
    float acc = pb[0] * f;
    const float* af = attf + ((size_t)b * 196) * R + d;
    for (int s = 0; s < 196; ++s) acc = fmaf(pb[1 + s], af[(size_t)s * R], acc);
    float beta = pb[196];
    huu_in[(size_t)b * 3072 + 2048 + d] = beta * f + (1.0f - beta) * acc;
}

__global__ __launch_bounds__(256) void copy_rows_kernel(
    float* __restrict__ dst, int ldd, const float* __restrict__ src, int lds_,
    int rows, int cols4)
{
    int idx = blockIdx.x * 256 + threadIdx.x;
    if (idx >= rows * cols4) return;
    int r = idx / cols4, c = (idx - r * cols4) * 4;
    *(float4*)(dst + (size_t)r * ldd + c) = *(const float4*)(src + (size_t)r * lds_ + c);
}

__global__ __launch_bounds__(256) void zero_kernel(float* __restrict__ p, int n)
{
    int idx = blockIdx.x * 256 + threadIdx.x;
    if (idx < n) p[idx] = 0.0f;
}

extern "C" void kernel_launch(void* const* d_in, const int* in_sizes, int n_in,
                              void* d_out, int out_size, void* d_ws, size_t ws_size,
                              hipStream_t stream)
{
    const float* xt         = (const float*)d_in[0];
    const float* state_h    = (const float*)d_in[1];
    const float* state_c    = (const float*)d_in[2];
    const float* fc_feats   = (const float*)d_in[3];
    const float* att_feats  = (const float*)d_in[4];
    const float* obj_feats  = (const float*)d_in[5];
    const float* attr_feats = (const float*)d_in[6];
    const float* rela_feats = (const float*)d_in[7];
    const float* p_obj      = (const float*)d_in[8];
    const float* p_attr     = (const float*)d_in[9];
    const float* p_rela     = (const float*)d_in[10];
    const float* att_masks  = (const float*)d_in[11];
    const float* rela_masks = (const float*)d_in[12];
    const float* att_wih    = (const float*)d_in[13];
    const float* att_whh    = (const float*)d_in[14];
    const float* att_bih    = (const float*)d_in[15];
    const float* att_bhh    = (const float*)d_in[16];
    const float* lang_wih   = (const float*)d_in[17];
    const float* lang_whh   = (const float*)d_in[18];
    const float* lang_bih   = (const float*)d_in[19];
    const float* lang_bhh   = (const float*)d_in[20];
    const float* xt2_w      = (const float*)d_in[21];
    const float* xt2_b      = (const float*)d_in[22];
    const float* h_att2_w   = (const float*)d_in[23];
    const float* h_att2_b   = (const float*)d_in[24];
    const float* r_i2h_w    = (const float*)d_in[25];
    const float* r_i2h_b    = (const float*)d_in[26];
    const float* r_h2h_w    = (const float*)d_in[27];
    const float* r_h2h_b    = (const float*)d_in[28];
    const float* huu_w      = (const float*)d_in[29];
    const float* huu_b      = (const float*)d_in[30];
    const float* obj_h2att_w  = (const float*)d_in[31];
    const float* obj_h2att_b  = (const float*)d_in[32];
    const float* obj_alpha_w  = (const float*)d_in[33];
    const float* attr_h2att_w = (const float*)d_in[35];
    const float* attr_h2att_b = (const float*)d_in[36];
    const float* attr_alpha_w = (const float*)d_in[37];
    const float* rela_h2att_w = (const float*)d_in[39];
    const float* rela_h2att_b = (const float*)d_in[40];
    const float* rela_alpha_w = (const float*)d_in[41];
    const float* fr_lin_w   = (const float*)d_in[43];
    const float* fr_lin_b   = (const float*)d_in[44];
    const float* fr_emb_w   = (const float*)d_in[45];
    const float* fr_emb_b   = (const float*)d_in[46];
    const float* ho_lin_w   = (const float*)d_in[47];
    const float* ho_lin_b   = (const float*)d_in[48];
    const float* ho_emb_w   = (const float*)d_in[49];
    const float* ho_emb_b   = (const float*)d_in[50];
    const float* ada_w      = (const float*)d_in[51];
    const float* cfe_w      = (const float*)d_in[53];
    const float* cfe_b      = (const float*)d_in[54];

    float* out = (float*)d_out;
    float* wsf = (float*)d_ws;

    // ws layout (floats)
    float* att_in    = wsf + 0;        // 128x3072
    float* g         = wsf + 393216;   // 128x4096 (att gates, then lang gates)
    float* h_att_raw = wsf + 917504;   // 128x1024
    float* lang_in   = wsf + 1048576;  // 128x4096 = [h_att|att_obj|att_attr|att_rela]
    float* att_h     = wsf + 1572864;  // 128x512
    float* e_w       = wsf + 1638400;  // 128x197 (also reused for module e/w)
    float* n5        = wsf + 1663616;  // 128x1024
    float* st        = wsf + 1794688;  // 128x1024
    float* fr        = wsf + 1925760;  // 128x1024 fake_region
    float* fre       = wsf + 2056832;  // 128x1024 fr_embed
    float* ho        = wsf + 2187904;  // 128x1024
    float* hoe       = wsf + 2318976;  // 128x1024 ho_embed
    float* huu_in    = wsf + 2450048;  // 128x3072

    float* h_att_out  = out + 131072;  // new_h[0]
    float* h_lang_out = out + 262144;  // new_h[1]
    float* c_att_out  = out + 393216;  // new_c[0]
    float* c_lang_out = out + 524288;  // new_c[1]

    const float* prev_h = state_h + 131072;  // state_h[1]

    auto GEMM = [&](const float* A, int lda, const float* W, const float* bias,
                    float* C, int ldc, int M, int N, int K, int addC, int act) {
        dim3 grid(N / 64, M / 64);
        gemm_kernel<<<grid, 256, 0, stream>>>(A, lda, W, bias, C, ldc, K, addC, act);
    };

    // att_in = [prev_h, fc_feats, xt]
    copy_rows_kernel<<<128, 256, 0, stream>>>(att_in + 0,    3072, prev_h,   1024, B, 256);
    copy_rows_kernel<<<128, 256, 0, stream>>>(att_in + 1024, 3072, fc_feats, 1024, B, 256);
    copy_rows_kernel<<<128, 256, 0, stream>>>(att_in + 2048, 3072, xt,       1024, B, 256);

    // att LSTM gates + cell
    GEMM(att_in, 3072, att_wih, att_bih, g, 4096, B, 4096, 3072, 0, 0);
    GEMM(state_h, 1024, att_whh, att_bhh, g, 4096, B, 4096, 1024, 1, 0);
    lstm_kernel<<<512, 256, 0, stream>>>(g, state_c, h_att_raw, c_att_out);

    // h_att = xt@xt2^T + b + h_att_raw@h_att2^T + b  (into lang_in[:,0:1024])
    GEMM(xt, 1024, xt2_w, xt2_b, lang_in, 4096, B, 1024, 1024, 0, 0);
    GEMM(h_att_raw, 1024, h_att2_w, h_att2_b, lang_in, 4096, B, 1024, 1024, 1, 0);
    copy_rows_kernel<<<128, 256, 0, stream>>>(h_att_out, 1024, lang_in, 4096, B, 256);

    // three attention modules -> lang_in columns 1024/2048/3072
    struct Mod { const float* feats; const float* p; const float* mask;
                 const float* w2; const float* b2; const float* aw; int S; int dst; };
    Mod mods[3] = {
        { obj_feats,  p_obj,  att_masks,  obj_h2att_w,  obj_h2att_b,  obj_alpha_w,  196, 1024 },
        { attr_feats, p_attr, att_masks,  attr_h2att_w, attr_h2att_b, attr_alpha_w, 196, 2048 },
        { rela_feats, p_rela, rela_masks, rela_h2att_w, rela_h2att_b, rela_alpha_w,  64, 3072 },
    };
    for (int m = 0; m < 3; ++m) {
        GEMM(lang_in, 4096, mods[m].w2, mods[m].b2, att_h, 512, B, 512, 1024, 0, 0);
        att_e_kernel<<<B * mods[m].S / 4, 256, 0, stream>>>(mods[m].p, att_h, mods[m].aw, e_w, mods[m].S);
        softmax_kernel<<<B, 256, 0, stream>>>(e_w, mods[m].mask, mods[m].S);
        wsum_kernel<<<512, 256, 0, stream>>>(e_w, mods[m].feats, lang_in + mods[m].dst, 4096, mods[m].S);
    }

    // lang LSTM
    GEMM(lang_in, 4096, lang_wih, lang_bih, g, 4096, B, 4096, 4096, 0, 0);
    GEMM(prev_h, 1024, lang_whh, lang_bhh, g, 4096, B, 4096, 1024, 1, 0);
    lstm_kernel<<<512, 256, 0, stream>>>(g, state_c + 131072, h_lang_out, c_lang_out);

    // n5 / st
    GEMM(lang_in, 4096, r_i2h_w, r_i2h_b, n5, 1024, B, 1024, 4096, 0, 0);
    GEMM(prev_h, 1024, r_h2h_w, r_h2h_b, n5, 1024, B, 1024, 1024, 1, 0);
    st_kernel<<<512, 256, 0, stream>>>(n5, c_lang_out, st);

    // fake_region chain and ho chain
    GEMM(st, 1024, fr_lin_w, fr_lin_b, fr, 1024, B, 1024, 1024, 0, 1);     // relu
    GEMM(fr, 1024, fr_emb_w, fr_emb_b, fre, 1024, B, 1024, 1024, 0, 0);
    GEMM(h_lang_out, 1024, ho_lin_w, ho_lin_b, ho, 1024, B, 1024, 1024, 0, 2);  // tanh
    GEMM(ho, 1024, ho_emb_w, ho_emb_b, hoe, 1024, B, 1024, 1024, 0, 0);

    // adaptive attention e (197): slot 0 from fr_embed, 1..196 fused cfe GEMM
    zero_kernel<<<99, 256, 0, stream>>>(e_w, 25216);
    ada_e0_kernel<<<32, 256, 0, stream>>>(fre, hoe, ada_w, e_w);
    {
        dim3 grid(1024 / 64, 25088 / 64);
        cfe_e_kernel<<<grid, 256, 0, stream>>>(p_obj, cfe_w, cfe_b, hoe, ada_w, e_w);
    }
    softmax_kernel<<<B, 256, 0, stream>>>(e_w, nullptr, 197);
    ct_kernel<<<512, 256, 0, stream>>>(e_w, fr, att_feats, huu_in);

    // output = [h_att, h_lang, c_t_hat] @ huu^T + b
    copy_rows_kernel<<<128, 256, 0, stream>>>(huu_in + 0,    3072, lang_in,    4096, B, 256);
    copy_rows_kernel<<<128, 256, 0, stream>>>(huu_in + 1024, 3072, h_lang_out, 1024, B, 256);
    GEMM(huu_in, 3072, huu_w, huu_b, out, 1024, B, 1024, 3072, 0, 0);

    (void)in_sizes; (void)n_in; (void)out_size; (void)ws_size;
}

// Round 2
// 1777.129 us; speedup vs baseline: 1.2514x; 1.2514x over previous
//
#include <hip/hip_runtime.h>
#include <cstddef>

#define B 128
#define R 1024

typedef __attribute__((ext_vector_type(8))) short short8;
typedef __attribute__((ext_vector_type(4))) float f32x4;

__device__ __forceinline__ float sigf(float x) { return 1.0f / (1.0f + __expf(-x)); }

__device__ __forceinline__ short f2bf(float f) {
    unsigned int u = __float_as_uint(f);
    u += 0x7fff + ((u >> 16) & 1);   // RNE
    return (short)(u >> 16);
}

__device__ __forceinline__ short8 cvt8(float4 u, float4 v) {
    short8 r;
    r[0] = f2bf(u.x); r[1] = f2bf(u.y); r[2] = f2bf(u.z); r[3] = f2bf(u.w);
    r[4] = f2bf(v.x); r[5] = f2bf(v.y); r[6] = f2bf(v.z); r[7] = f2bf(v.w);
    return r;
}

// ---------------------------------------------------------------------------
// bf16-MFMA GEMM, fp32 in/out, M=128 fixed, BN=128 per block, BK=32.
// Supports 2-segment K:  C = [A1|A2] @ [W1|W2]^T + b1 + b2, act.
// A1:(128,K1) lda1; A2:(128,Ktot-K1) lda2; W1:(N,K1); W2:(N,Ktot-K1).
// grid = (N/128), block = 256 (4 waves, each 64x64).
// ---------------------------------------------------------------------------
__global__ __launch_bounds__(256) void gemm_bf16_kernel(
    const float* __restrict__ A1, int lda1, int K1,
    const float* __restrict__ A2, int lda2,
    const float* __restrict__ W1, const float* __restrict__ W2,
    const float* __restrict__ b1, const float* __restrict__ b2,
    float* __restrict__ C, int ldc, int Ktot, int act)
{
    __shared__ short sA[128 * 40];
    __shared__ short sB[128 * 40];
    const int tid = threadIdx.x;
    const int r   = tid >> 1;           // 0..127 staging row
    const int kh  = (tid & 1) << 4;     // 0 or 16
    const int bn  = blockIdx.x * 128;
    const int lane = tid & 63;
    const int wid  = tid >> 6;
    const int wm   = (wid >> 1) * 64;
    const int wn   = (wid & 1) * 64;
    const int fr_  = lane & 15;
    const int kof  = (lane >> 4) * 8;
    const int K2   = Ktot - K1;

    f32x4 acc[4][4];
#pragma unroll
    for (int m = 0; m < 4; ++m)
#pragma unroll
        for (int n = 0; n < 4; ++n)
            acc[m][n] = (f32x4)0.0f;

    for (int k0 = 0; k0 < Ktot; k0 += 32) {
        int kg = k0 + kh;
        const float* pa;
        const float* pw;
        if (kg < K1) {
            pa = A1 + (size_t)r * lda1 + kg;
            pw = W1 + (size_t)(bn + r) * K1 + kg;
        } else {
            pa = A2 + (size_t)r * lda2 + (kg - K1);
            pw = W2 + (size_t)(bn + r) * K2 + (kg - K1);
        }
        float4 a0 = ((const float4*)pa)[0];
        float4 a1 = ((const float4*)pa)[1];
        float4 a2 = ((const float4*)pa)[2];
        float4 a3 = ((const float4*)pa)[3];
        float4 w0 = ((const float4*)pw)[0];
        float4 w1 = ((const float4*)pw)[1];
        float4 w2 = ((const float4*)pw)[2];
        float4 w3 = ((const float4*)pw)[3];
        __syncthreads();
        *(short8*)&sA[r * 40 + kh]     = cvt8(a0, a1);
        *(short8*)&sA[r * 40 + kh + 8] = cvt8(a2, a3);
        *(short8*)&sB[r * 40 + kh]     = cvt8(w0, w1);
        *(short8*)&sB[r * 40 + kh + 8] = cvt8(w2, w3);
        __syncthreads();
        short8 af[4], bf[4];
#pragma unroll
        for (int m = 0; m < 4; ++m)
            af[m] = *(const short8*)&sA[(wm + m * 16 + fr_) * 40 + kof];
#pragma unroll
        for (int n = 0; n < 4; ++n)
            bf[n] = *(const short8*)&sB[(wn + n * 16 + fr_) * 40 + kof];
#pragma unroll
        for (int m = 0; m < 4; ++m)
#pragma unroll
            for (int n = 0; n < 4; ++n)
                acc[m][n] = __builtin_amdgcn_mfma_f32_16x16x32_bf16(af[m], bf[n], acc[m][n], 0, 0, 0);
    }

#pragma unroll
    for (int m = 0; m < 4; ++m) {
        int row0 = wm + m * 16 + ((lane >> 4) << 2);
#pragma unroll
        for (int n = 0; n < 4; ++n) {
            int col = bn + wn + n * 16 + fr_;
            float bsum = (b1 ? b1[col] : 0.0f) + (b2 ? b2[col] : 0.0f);
#pragma unroll
            for (int rg = 0; rg < 4; ++rg) {
                float v = acc[m][n][rg] + bsum;
                if (act == 1) v = fmaxf(v, 0.0f);
                else if (act == 2) v = tanhf(v);
                C[(size_t)(row0 + rg) * ldc + col] = v;
            }
        }
    }
}

// ---------------------------------------------------------------------------
// cfe GEMM (25088x1024x512) fused with tanh/dot/row-reduce epilogue.
// e[b*197+1+s] += sum_n tanh(P@W^T + cb + hoe[b]) * aw[n]
// grid = (1024/128, 25088/128) = (8,196), block 256.
// ---------------------------------------------------------------------------
__global__ __launch_bounds__(256) void cfe_mfma_kernel(
    const float* __restrict__ P,
    const float* __restrict__ W,
    const float* __restrict__ cb,
    const float* __restrict__ hoe,
    const float* __restrict__ aw,
    float* __restrict__ e)
{
    __shared__ short sA[128 * 40];
    __shared__ short sB[128 * 40];
    const int tid = threadIdx.x;
    const int r   = tid >> 1;
    const int kh  = (tid & 1) << 4;
    const int bn  = blockIdx.x * 128;
    const int bm  = blockIdx.y * 128;
    const int lane = tid & 63;
    const int wid  = tid >> 6;
    const int wm   = (wid >> 1) * 64;
    const int wn   = (wid & 1) * 64;
    const int fr_  = lane & 15;
    const int kof  = (lane >> 4) * 8;

    f32x4 acc[4][4];
#pragma unroll
    for (int m = 0; m < 4; ++m)
#pragma unroll
        for (int n = 0; n < 4; ++n)
            acc[m][n] = (f32x4)0.0f;

    for (int k0 = 0; k0 < 512; k0 += 32) {
        int kg = k0 + kh;
        const float* pa = P + (size_t)(bm + r) * 512 + kg;
        const float* pw = W + (size_t)(bn + r) * 512 + kg;
        float4 a0 = ((const float4*)pa)[0];
        float4 a1 = ((const float4*)pa)[1];
        float4 a2 = ((const float4*)pa)[2];
        float4 a3 = ((const float4*)pa)[3];
        float4 w0 = ((const float4*)pw)[0];
        float4 w1 = ((const float4*)pw)[1];
        float4 w2 = ((const float4*)pw)[2];
        float4 w3 = ((const float4*)pw)[3];
        __syncthreads();
        *(short8*)&sA[r * 40 + kh]     = cvt8(a0, a1);
        *(short8*)&sA[r * 40 + kh + 8] = cvt8(a2, a3);
        *(short8*)&sB[r * 40 + kh]     = cvt8(w0, w1);
        *(short8*)&sB[r * 40 + kh + 8] = cvt8(w2, w3);
        __syncthreads();
        short8 af[4], bf[4];
#pragma unroll
        for (int m = 0; m < 4; ++m)
            af[m] = *(const short8*)&sA[(wm + m * 16 + fr_) * 40 + kof];
#pragma unroll
        for (int n = 0; n < 4; ++n)
            bf[n] = *(const short8*)&sB[(wn + n * 16 + fr_) * 40 + kof];
#pragma unroll
        for (int m = 0; m < 4; ++m)
#pragma unroll
            for (int n = 0; n < 4; ++n)
                acc[m][n] = __builtin_amdgcn_mfma_f32_16x16x32_bf16(af[m], bf[n], acc[m][n], 0, 0, 0);
    }

#pragma unroll
    for (int m = 0; m < 4; ++m) {
#pragma unroll
        for (int rg = 0; rg < 4; ++rg) {
            int gr = bm + wm + m * 16 + ((lane >> 4) << 2) + rg;   // 0..25087
            int b = gr / 196, s = gr - b * 196;
            float part = 0.0f;
#pragma unroll
            for (int n = 0; n < 4; ++n) {
                int col = bn + wn + n * 16 + fr_;
                part += tanhf(acc[m][n][rg] + cb[col] + hoe[(size_t)b * R + col]) * aw[col];
            }
            part += __shfl_xor(part, 1);
            part += __shfl_xor(part, 2);
            part += __shfl_xor(part, 4);
            part += __shfl_xor(part, 8);
            if ((lane & 15) == 0)
                atomicAdd(&e[b * 197 + 1 + s], part);
        }
    }
}

// e[b,s] = sum_a tanh(p[b,s,a] + ah[b,a]) * aw[a]   (one wave per (b,s))
__global__ __launch_bounds__(256) void att_e_kernel(
    const float* __restrict__ p, const float* __restrict__ ah,
    const float* __restrict__ aw, float* __restrict__ e, int S)
{
    int wid = threadIdx.x >> 6, lane = threadIdx.x & 63;
    int idx = blockIdx.x * 4 + wid;   // b*S + s
    int b = idx / S;
    const float* pr = p + (size_t)idx * 512;
    const float* ab = ah + (size_t)b * 512;
    float sum = 0.0f;
#pragma unroll
    for (int k = 0; k < 8; ++k) {
        int a = k * 64 + lane;
        sum += tanhf(pr[a] + ab[a]) * aw[a];
    }
#pragma unroll
    for (int off = 32; off; off >>= 1) sum += __shfl_down(sum, off);
    if (lane == 0) e[idx] = sum;
}

// softmax over S (<=256) per row b, optional mask, renormalize. in-place.
__global__ __launch_bounds__(256) void softmax_kernel(
    float* __restrict__ e, const float* __restrict__ mask, int S)
{
    __shared__ float red[256];
    int b = blockIdx.x, tid = threadIdx.x;
    float v = (tid < S) ? e[(size_t)b * S + tid] : -3.4e38f;
    red[tid] = v; __syncthreads();
    for (int s = 128; s; s >>= 1) { if (tid < s) red[tid] = fmaxf(red[tid], red[tid + s]); __syncthreads(); }
    float m = red[0]; __syncthreads();
    float p = (tid < S) ? __expf(v - m) : 0.0f;
    red[tid] = p; __syncthreads();
    for (int s = 128; s; s >>= 1) { if (tid < s) red[tid] += red[tid + s]; __syncthreads(); }
    float s1 = red[0]; __syncthreads();
    float w = p / s1;
    if (mask && tid < S) w *= mask[(size_t)b * S + tid];
    red[tid] = (tid < S) ? w : 0.0f; __syncthreads();
    for (int s = 128; s; s >>= 1) { if (tid < s) red[tid] += red[tid + s]; __syncthreads(); }
    float s2 = red[0];
    if (tid < S) e[(size_t)b * S + tid] = w / s2;
}

// out[b, d] = sum_s w[b,s] * feats[b,s,d]   grid = B*4 blocks x 256 threads
__global__ __launch_bounds__(256) void wsum_kernel(
    const float* __restrict__ w, const float* __restrict__ feats,
    float* __restrict__ out, int ldo, int S)
{
    int idx = blockIdx.x * 256 + threadIdx.x;
    int b = idx >> 10, d = idx & 1023;
    const float* f = feats + ((size_t)b * S) * R + d;
    const float* wb = w + (size_t)b * S;
    float acc = 0.0f;
    for (int s = 0; s < S; ++s) acc = fmaf(wb[s], f[(size_t)s * R], acc);
    out[(size_t)b * ldo + d] = acc;
}

__global__ __launch_bounds__(256) void lstm_kernel(
    const float* __restrict__ g, const float* __restrict__ cprev,
    float* __restrict__ h, float* __restrict__ c)
{
    int idx = blockIdx.x * 256 + threadIdx.x;  // b*1024 + d
    int b = idx >> 10, d = idx & 1023;
    const float* gr = g + (size_t)b * 4096;
    float iv = sigf(gr[d]);
    float fv = sigf(gr[1024 + d]);
    float gv = tanhf(gr[2048 + d]);
    float ov = sigf(gr[3072 + d]);
    float c2 = fv * cprev[idx] + iv * gv;
    c[idx] = c2;
    h[idx] = ov * tanhf(c2);
}

// st = sigmoid(n5) * tanh(c_lang)
__global__ __launch_bounds__(256) void st_kernel(
    const float* __restrict__ n5, const float* __restrict__ clang, float* __restrict__ st)
{
    int idx = blockIdx.x * 256 + threadIdx.x;
    st[idx] = sigf(n5[idx]) * tanhf(clang[idx]);
}

// e[b*197] = sum_r tanh(fre[b,r]+hoe[b,r])*aw[r]  (one wave per b)
__global__ __launch_bounds__(256) void ada_e0_kernel(
    const float* __restrict__ fre, const float* __restrict__ hoe,
    const float* __restrict__ aw, float* __restrict__ e)
{
    int wid = threadIdx.x >> 6, lane = threadIdx.x & 63;
    int b = blockIdx.x * 4 + wid;
    float sum = 0.0f;
#pragma unroll
    for (int k = 0; k < 16; ++k) {
        int r = k * 64 + lane;
        sum += tanhf(fre[(size_t)b * R + r] + hoe[(size_t)b * R + r]) * aw[r];
    }
#pragma unroll
    for (int off = 32; off; off >>= 1) sum += __shfl_down(sum, off);
    if (lane == 0) e[b * 197] = sum;
}

// c_t_hat into huu_in[:, 2048:3072]
__global__ __launch_bounds__(256) void ct_kernel(
    const float* __restrict__ PI, const float* __restrict__ fr,
    const float* __restrict__ attf, float* __restrict__ huu_in)
{
    int idx = blockIdx.x * 256 + threadIdx.x;
    int b = idx >> 10, d = idx & 1023;
    float f = fr[idx];
    const float* pb = PI + b * 197;
    float acc = pb[0] * f;
    const float* af = attf + ((size_t)b * 196) * R + d;
    for (int s = 0; s < 196; ++s) acc = fmaf(pb[1 + s], af[(size_t)s * R], acc);
    float beta = pb[196];
    huu_in[(size_t)b * 3072 + 2048 + d] = beta * f + (1.0f - beta) * acc;
}

__global__ __launch_bounds__(256) void copy_rows_kernel(
    float* __restrict__ dst, int ldd, const float* __restrict__ src, int lds_,
    int rows, int cols4)
{
    int idx = blockIdx.x * 256 + threadIdx.x;
    if (idx >= rows * cols4) return;
    int r = idx / cols4, c = (idx - r * cols4) * 4;
    *(float4*)(dst + (size_t)r * ldd + c) = *(const float4*)(src + (size_t)r * lds_ + c);
}

__global__ __launch_bounds__(256) void zero_kernel(float* __restrict__ p, int n)
{
    int idx = blockIdx.x * 256 + threadIdx.x;
    if (idx < n) p[idx] = 0.0f;
}

extern "C" void kernel_launch(void* const* d_in, const int* in_sizes, int n_in,
                              void* d_out, int out_size, void* d_ws, size_t ws_size,
                              hipStream_t stream)
{
    const float* xt         = (const float*)d_in[0];
    const float* state_h    = (const float*)d_in[1];
    const float* state_c    = (const float*)d_in[2];
    const float* fc_feats   = (const float*)d_in[3];
    const float* att_feats  = (const float*)d_in[4];
    const float* obj_feats  = (const float*)d_in[5];
    const float* attr_feats = (const float*)d_in[6];
    const float* rela_feats = (const float*)d_in[7];
    const float* p_obj      = (const float*)d_in[8];
    const float* p_attr     = (const float*)d_in[9];
    const float* p_rela     = (const float*)d_in[10];
    const float* att_masks  = (const float*)d_in[11];
    const float* rela_masks = (const float*)d_in[12];
    const float* att_wih    = (const float*)d_in[13];
    const float* att_whh    = (const float*)d_in[14];
    const float* att_bih    = (const float*)d_in[15];
    const float* att_bhh    = (const float*)d_in[16];
    const float* lang_wih   = (const float*)d_in[17];
    const float* lang_whh   = (const float*)d_in[18];
    const float* lang_bih   = (const float*)d_in[19];
    const float* lang_bhh   = (const float*)d_in[20];
    const float* xt2_w      = (const float*)d_in[21];
    const float* xt2_b      = (const float*)d_in[22];
    const float* h_att2_w   = (const float*)d_in[23];
    const float* h_att2_b   = (const float*)d_in[24];
    const float* r_i2h_w    = (const float*)d_in[25];
    const float* r_i2h_b    = (const float*)d_in[26];
    const float* r_h2h_w    = (const float*)d_in[27];
    const float* r_h2h_b    = (const float*)d_in[28];
    const float* huu_w      = (const float*)d_in[29];
    const float* huu_b      = (const float*)d_in[30];
    const float* obj_h2att_w  = (const float*)d_in[31];
    const float* obj_h2att_b  = (const float*)d_in[32];
    const float* obj_alpha_w  = (const float*)d_in[33];
    const float* attr_h2att_w = (const float*)d_in[35];
    const float* attr_h2att_b = (const float*)d_in[36];
    const float* attr_alpha_w = (const float*)d_in[37];
    const float* rela_h2att_w = (const float*)d_in[39];
    const float* rela_h2att_b = (const float*)d_in[40];
    const float* rela_alpha_w = (const float*)d_in[41];
    const float* fr_lin_w   = (const float*)d_in[43];
    const float* fr_lin_b   = (const float*)d_in[44];
    const float* fr_emb_w   = (const float*)d_in[45];
    const float* fr_emb_b   = (const float*)d_in[46];
    const float* ho_lin_w   = (const float*)d_in[47];
    const float* ho_lin_b   = (const float*)d_in[48];
    const float* ho_emb_w   = (const float*)d_in[49];
    const float* ho_emb_b   = (const float*)d_in[50];
    const float* ada_w      = (const float*)d_in[51];
    const float* cfe_w      = (const float*)d_in[53];
    const float* cfe_b      = (const float*)d_in[54];

    float* out = (float*)d_out;
    float* wsf = (float*)d_ws;

    // ws layout (floats)
    float* att_in    = wsf + 0;        // 128x3072
    float* g         = wsf + 393216;   // 128x4096 (att gates, then lang gates)
    float* h_att_raw = wsf + 917504;   // 128x1024
    float* lang_in   = wsf + 1048576;  // 128x4096 = [h_att|att_obj|att_attr|att_rela]
    float* att_h     = wsf + 1572864;  // 128x512
    float* e_w       = wsf + 1638400;  // 128x197 / per-module e
    float* n5        = wsf + 1663616;  // 128x1024
    float* st        = wsf + 1794688;  // 128x1024
    float* fr        = wsf + 1925760;  // 128x1024 fake_region
    float* fre       = wsf + 2056832;  // 128x1024 fr_embed
    float* ho        = wsf + 2187904;  // 128x1024
    float* hoe       = wsf + 2318976;  // 128x1024 ho_embed
    float* huu_in    = wsf + 2450048;  // 128x3072

    float* h_att_out  = out + 131072;  // new_h[0]
    float* h_lang_out = out + 262144;  // new_h[1]
    float* c_att_out  = out + 393216;  // new_c[0]
    float* c_lang_out = out + 524288;  // new_c[1]

    const float* prev_h = state_h + 131072;  // state_h[1]

    auto GEMM = [&](const float* A1, int lda1, int K1, const float* A2, int lda2,
                    const float* W1, const float* W2, const float* b1, const float* b2,
                    float* C, int ldc, int N, int Ktot, int act) {
        gemm_bf16_kernel<<<dim3(N / 128), 256, 0, stream>>>(
            A1, lda1, K1, A2, lda2, W1, W2, b1, b2, C, ldc, Ktot, act);
    };

    // att_in = [prev_h, fc_feats, xt]
    copy_rows_kernel<<<128, 256, 0, stream>>>(att_in + 0,    3072, prev_h,   1024, B, 256);
    copy_rows_kernel<<<128, 256, 0, stream>>>(att_in + 1024, 3072, fc_feats, 1024, B, 256);
    copy_rows_kernel<<<128, 256, 0, stream>>>(att_in + 2048, 3072, xt,       1024, B, 256);

    // att LSTM: g = [att_in | h0] @ [wih|whh]^T + bih + bhh
    GEMM(att_in, 3072, 3072, state_h, 1024,
         att_wih, att_whh, att_bih, att_bhh, g, 4096, 4096, 4096, 0);
    lstm_kernel<<<512, 256, 0, stream>>>(g, state_c, h_att_raw, c_att_out);

    // h_att = [xt | h_att_raw] @ [xt2|h_att2]^T + b + b  -> lang_in[:,0:1024]
    GEMM(xt, 1024, 1024, h_att_raw, 1024,
         xt2_w, h_att2_w, xt2_b, h_att2_b, lang_in, 4096, 1024, 2048, 0);
    copy_rows_kernel<<<128, 256, 0, stream>>>(h_att_out, 1024, lang_in, 4096, B, 256);

    // three attention modules -> lang_in columns 1024/2048/3072
    struct Mod { const float* feats; const float* p; const float* mask;
                 const float* w2; const float* b2; const float* aw; int S; int dst; };
    Mod mods[3] = {
        { obj_feats,  p_obj,  att_masks,  obj_h2att_w,  obj_h2att_b,  obj_alpha_w,  196, 1024 },
        { attr_feats, p_attr, att_masks,  attr_h2att_w, attr_h2att_b, attr_alpha_w, 196, 2048 },
        { rela_feats, p_rela, rela_masks, rela_h2att_w, rela_h2att_b, rela_alpha_w,  64, 3072 },
    };
    for (int m = 0; m < 3; ++m) {
        GEMM(lang_in, 4096, 1024, nullptr, 0,
             mods[m].w2, nullptr, mods[m].b2, nullptr, att_h, 512, 512, 1024, 0);
        att_e_kernel<<<B * mods[m].S / 4, 256, 0, stream>>>(mods[m].p, att_h, mods[m].aw, e_w, mods[m].S);
        softmax_kernel<<<B, 256, 0, stream>>>(e_w, mods[m].mask, mods[m].S);
        wsum_kernel<<<512, 256, 0, stream>>>(e_w, mods[m].feats, lang_in + mods[m].dst, 4096, mods[m].S);
    }

    // lang LSTM: g = [lang_in | prev_h] @ [wih|whh]^T + biases
    GEMM(lang_in, 4096, 4096, prev_h, 1024,
         lang_wih, lang_whh, lang_bih, lang_bhh, g, 4096, 4096, 5120, 0);
    lstm_kernel<<<512, 256, 0, stream>>>(g, state_c + 131072, h_lang_out, c_lang_out);

    // n5 = [lang_in | prev_h] @ [r_i2h|r_h2h]^T + biases ; st
    GEMM(lang_in, 4096, 4096, prev_h, 1024,
         r_i2h_w, r_h2h_w, r_i2h_b, r_h2h_b, n5, 1024, 1024, 5120, 0);
    st_kernel<<<512, 256, 0, stream>>>(n5, c_lang_out, st);

    // fake_region chain and ho chain
    GEMM(st, 1024, 1024, nullptr, 0, fr_lin_w, nullptr, fr_lin_b, nullptr, fr, 1024, 1024, 1024, 1);
    GEMM(fr, 1024, 1024, nullptr, 0, fr_emb_w, nullptr, fr_emb_b, nullptr, fre, 1024, 1024, 1024, 0);
    GEMM(h_lang_out, 1024, 1024, nullptr, 0, ho_lin_w, nullptr, ho_lin_b, nullptr, ho, 1024, 1024, 1024, 2);
    GEMM(ho, 1024, 1024, nullptr, 0, ho_emb_w, nullptr, ho_emb_b, nullptr, hoe, 1024, 1024, 1024, 0);

    // adaptive attention e (197): slot 0 from fr_embed, 1..196 fused cfe GEMM
    zero_kernel<<<99, 256, 0, stream>>>(e_w, 25216);
    ada_e0_kernel<<<32, 256, 0, stream>>>(fre, hoe, ada_w, e_w);
    {
        dim3 grid(8, 196);
        cfe_mfma_kernel<<<grid, 256, 0, stream>>>(p_obj, cfe_w, cfe_b, hoe, ada_w, e_w);
    }
    softmax_kernel<<<B, 256, 0, stream>>>(e_w, nullptr, 197);
    ct_kernel<<<512, 256, 0, stream>>>(e_w, fr, att_feats, huu_in);

    // output = [h_att, h_lang, c_t_hat] @ huu^T + b
    copy_rows_kernel<<<128, 256, 0, stream>>>(huu_in + 0,    3072, lang_in,    4096, B, 256);
    copy_rows_kernel<<<128, 256, 0, stream>>>(huu_in + 1024, 3072, h_lang_out, 1024, B, 256);
    GEMM(huu_in, 3072, 3072, nullptr, 0, huu_w, nullptr, huu_b, nullptr, out, 1024, 1024, 3072, 0);

    (void)in_sizes; (void)n_in; (void)out_size; (void)ws_size;
}

// Round 3
// 538.447 us; speedup vs baseline: 4.1301x; 3.3005x over previous
//
#include <hip/hip_runtime.h>
#include <cstddef>

#define B 128
#define R 1024

typedef __attribute__((ext_vector_type(8))) short short8;
typedef __attribute__((ext_vector_type(4))) float f32x4;

__device__ __forceinline__ float sigf(float x) { return 1.0f / (1.0f + __expf(-x)); }

__device__ __forceinline__ short f2bf(float f) {
    unsigned int u = __float_as_uint(f);
    u += 0x7fff + ((u >> 16) & 1);   // RNE
    return (short)(u >> 16);
}

__device__ __forceinline__ short8 cvt8(float4 u, float4 v) {
    short8 r;
    r[0] = f2bf(u.x); r[1] = f2bf(u.y); r[2] = f2bf(u.z); r[3] = f2bf(u.w);
    r[4] = f2bf(v.x); r[5] = f2bf(v.y); r[6] = f2bf(v.z); r[7] = f2bf(v.w);
    return r;
}

// ---------------------------------------------------------------------------
// Split-K multi-job bf16-MFMA GEMM. M=128, BN=64, BK=32, 4 waves (each 32x64).
// C[m,n] += sum_k A[m,k]*W[n,k]  via atomicAdd (C pre-zeroed; bias in epilogue).
// A is up to 3 concatenated K-segments; W segments have independent lds.
// grid = (sum of job nb, SK). Kchunk = Ktot/SK (multiple of 32).
// ---------------------------------------------------------------------------
struct GJob {
    const float* A1; const float* A2; const float* A3;
    const float* W1; const float* W2; const float* W3;
    float* C;
    int lda1, lda2, lda3;
    int ldw1, ldw2, ldw3;
    int K1, K12, Ktot;
    int ldc, Kchunk, nb;
};

__global__ __launch_bounds__(256) void gemm_sk_kernel(GJob j0, GJob j1, GJob j2, int njobs)
{
    GJob j = j0;
    int nbx = blockIdx.x;
    if (njobs > 1 && nbx >= j.nb) { nbx -= j.nb; j = j1; }
    if (njobs > 2 && nbx >= j.nb) { nbx -= j.nb; j = j2; }

    const int bn   = nbx * 64;
    const int kbeg = blockIdx.y * j.Kchunk;
    const int kend = kbeg + j.Kchunk;

    __shared__ short sA[128 * 40];
    __shared__ short sB[64 * 40];
    const int tid  = threadIdx.x;
    const int rA   = tid >> 1;          // 0..127
    const int kha  = (tid & 1) << 4;    // 0/16
    const int rB   = tid >> 2;          // 0..63
    const int khb  = (tid & 3) << 3;    // 0/8/16/24
    const int lane = tid & 63;
    const int wid  = tid >> 6;
    const int wm   = wid * 32;
    const int fr_  = lane & 15;
    const int kof  = (lane >> 4) * 8;

    f32x4 acc[2][4];
#pragma unroll
    for (int m = 0; m < 2; ++m)
#pragma unroll
        for (int n = 0; n < 4; ++n)
            acc[m][n] = (f32x4)0.0f;

    for (int k0 = kbeg; k0 < kend; k0 += 32) {
        int kgA = k0 + kha;
        const float* pa;
        if (kgA < j.K1)       pa = j.A1 + (size_t)rA * j.lda1 + kgA;
        else if (kgA < j.K12) pa = j.A2 + (size_t)rA * j.lda2 + (kgA - j.K1);
        else                  pa = j.A3 + (size_t)rA * j.lda3 + (kgA - j.K12);
        int kgB = k0 + khb;
        const float* pw;
        if (kgB < j.K1)       pw = j.W1 + (size_t)(bn + rB) * j.ldw1 + kgB;
        else if (kgB < j.K12) pw = j.W2 + (size_t)(bn + rB) * j.ldw2 + (kgB - j.K1);
        else                  pw = j.W3 + (size_t)(bn + rB) * j.ldw3 + (kgB - j.K12);

        float4 a0 = ((const float4*)pa)[0];
        float4 a1 = ((const float4*)pa)[1];
        float4 a2 = ((const float4*)pa)[2];
        float4 a3 = ((const float4*)pa)[3];
        float4 w0 = ((const float4*)pw)[0];
        float4 w1 = ((const float4*)pw)[1];
        __syncthreads();
        *(short8*)&sA[rA * 40 + kha]     = cvt8(a0, a1);
        *(short8*)&sA[rA * 40 + kha + 8] = cvt8(a2, a3);
        *(short8*)&sB[rB * 40 + khb]     = cvt8(w0, w1);
        __syncthreads();
        short8 af[2], bf[4];
#pragma unroll
        for (int m = 0; m < 2; ++m)
            af[m] = *(const short8*)&sA[(wm + m * 16 + fr_) * 40 + kof];
#pragma unroll
        for (int n = 0; n < 4; ++n)
            bf[n] = *(const short8*)&sB[(n * 16 + fr_) * 40 + kof];
#pragma unroll
        for (int m = 0; m < 2; ++m)
#pragma unroll
            for (int n = 0; n < 4; ++n)
                acc[m][n] = __builtin_amdgcn_mfma_f32_16x16x32_bf16(af[m], bf[n], acc[m][n], 0, 0, 0);
    }

#pragma unroll
    for (int m = 0; m < 2; ++m) {
        int row0 = wm + m * 16 + ((lane >> 4) << 2);
#pragma unroll
        for (int n = 0; n < 4; ++n) {
            int col = bn + n * 16 + fr_;
#pragma unroll
            for (int rg = 0; rg < 4; ++rg)
                atomicAdd(&j.C[(size_t)(row0 + rg) * j.ldc + col], acc[m][n][rg]);
        }
    }
}

// ---------------------------------------------------------------------------
// cfe GEMM (25088x1024x512) fused with tanh/dot/row-reduce epilogue.
// ---------------------------------------------------------------------------
__global__ __launch_bounds__(256) void cfe_mfma_kernel(
    const float* __restrict__ P,
    const float* __restrict__ W,
    const float* __restrict__ cb,
    const float* __restrict__ hoe,   // raw (no bias)
    const float* __restrict__ ho_b,
    const float* __restrict__ aw,
    float* __restrict__ e)
{
    __shared__ short sA[128 * 40];
    __shared__ short sB[128 * 40];
    const int tid = threadIdx.x;
    const int r   = tid >> 1;
    const int kh  = (tid & 1) << 4;
    const int bn  = blockIdx.x * 128;
    const int bm  = blockIdx.y * 128;
    const int lane = tid & 63;
    const int wid  = tid >> 6;
    const int wm   = (wid >> 1) * 64;
    const int wn   = (wid & 1) * 64;
    const int fr_  = lane & 15;
    const int kof  = (lane >> 4) * 8;

    f32x4 acc[4][4];
#pragma unroll
    for (int m = 0; m < 4; ++m)
#pragma unroll
        for (int n = 0; n < 4; ++n)
            acc[m][n] = (f32x4)0.0f;

    for (int k0 = 0; k0 < 512; k0 += 32) {
        int kg = k0 + kh;
        const float* pa = P + (size_t)(bm + r) * 512 + kg;
        const float* pw = W + (size_t)(bn + r) * 512 + kg;
        float4 a0 = ((const float4*)pa)[0];
        float4 a1 = ((const float4*)pa)[1];
        float4 a2 = ((const float4*)pa)[2];
        float4 a3 = ((const float4*)pa)[3];
        float4 w0 = ((const float4*)pw)[0];
        float4 w1 = ((const float4*)pw)[1];
        float4 w2 = ((const float4*)pw)[2];
        float4 w3 = ((const float4*)pw)[3];
        __syncthreads();
        *(short8*)&sA[r * 40 + kh]     = cvt8(a0, a1);
        *(short8*)&sA[r * 40 + kh + 8] = cvt8(a2, a3);
        *(short8*)&sB[r * 40 + kh]     = cvt8(w0, w1);
        *(short8*)&sB[r * 40 + kh + 8] = cvt8(w2, w3);
        __syncthreads();
        short8 af[4], bf[4];
#pragma unroll
        for (int m = 0; m < 4; ++m)
            af[m] = *(const short8*)&sA[(wm + m * 16 + fr_) * 40 + kof];
#pragma unroll
        for (int n = 0; n < 4; ++n)
            bf[n] = *(const short8*)&sB[(wn + n * 16 + fr_) * 40 + kof];
#pragma unroll
        for (int m = 0; m < 4; ++m)
#pragma unroll
            for (int n = 0; n < 4; ++n)
                acc[m][n] = __builtin_amdgcn_mfma_f32_16x16x32_bf16(af[m], bf[n], acc[m][n], 0, 0, 0);
    }

#pragma unroll
    for (int m = 0; m < 4; ++m) {
#pragma unroll
        for (int rg = 0; rg < 4; ++rg) {
            int gr = bm + wm + m * 16 + ((lane >> 4) << 2) + rg;   // 0..25087
            int b = gr / 196, s = gr - b * 196;
            float part = 0.0f;
#pragma unroll
            for (int n = 0; n < 4; ++n) {
                int col = bn + wn + n * 16 + fr_;
                part += tanhf(acc[m][n][rg] + cb[col] + ho_b[col] + hoe[(size_t)b * R + col]) * aw[col];
            }
            part += __shfl_xor(part, 1);
            part += __shfl_xor(part, 2);
            part += __shfl_xor(part, 4);
            part += __shfl_xor(part, 8);
            if ((lane & 15) == 0)
                atomicAdd(&e[b * 197 + 1 + s], part);
        }
    }
}

// zero atomic-target ws region + d_out
__global__ __launch_bounds__(256) void zero2_kernel(
    float* __restrict__ ws, int nws, float* __restrict__ o)
{
    int idx = blockIdx.x * 256 + threadIdx.x;
    if (idx < nws) ws[idx] = 0.0f;
    else o[idx - nws] = 0.0f;
}

// att_in = [prev_h | fc | xt]  (float4 granularity)
__global__ __launch_bounds__(256) void concat3_kernel(
    const float* __restrict__ a, const float* __restrict__ b2,
    const float* __restrict__ c, float* __restrict__ dst)
{
    int idx = blockIdx.x * 256 + threadIdx.x;   // over 128*768 float4s
    int r = idx / 768, c4 = idx - r * 768;
    int col = c4 * 4;
    const float* src = (col < 1024) ? (a + (size_t)r * 1024 + col)
                     : (col < 2048) ? (b2 + (size_t)r * 1024 + col - 1024)
                                    : (c + (size_t)r * 1024 + col - 2048);
    *(float4*)(dst + (size_t)r * 3072 + col) = *(const float4*)src;
}

// LSTM epilogue: gates g (raw) + bih + bhh -> h,c ; self-zero g for reuse.
__global__ __launch_bounds__(256) void lstm_kernel(
    float* __restrict__ g, const float* __restrict__ bih, const float* __restrict__ bhh,
    const float* __restrict__ cprev, float* __restrict__ h, float* __restrict__ c)
{
    int idx = blockIdx.x * 256 + threadIdx.x;  // b*1024 + d
    int b = idx >> 10, d = idx & 1023;
    float* gr = g + (size_t)b * 4096;
    float iv = sigf(gr[d]        + bih[d]        + bhh[d]);
    float fv = sigf(gr[1024 + d] + bih[1024 + d] + bhh[1024 + d]);
    float gv = tanhf(gr[2048 + d] + bih[2048 + d] + bhh[2048 + d]);
    float ov = sigf(gr[3072 + d] + bih[3072 + d] + bhh[3072 + d]);
    gr[d] = 0.0f; gr[1024 + d] = 0.0f; gr[2048 + d] = 0.0f; gr[3072 + d] = 0.0f;
    float c2 = fv * cprev[idx] + iv * gv;
    c[idx] = c2;
    h[idx] = ov * tanhf(c2);
}

// h_att epilogue: lang_in[:,0:1024] += biases (in place) and copy to h_att_out
__global__ __launch_bounds__(256) void hatt_epi_kernel(
    float* __restrict__ lang_in, const float* __restrict__ b1,
    const float* __restrict__ b2, float* __restrict__ h_att_out)
{
    int idx = blockIdx.x * 256 + threadIdx.x;  // 128*1024
    int r = idx >> 10, c = idx & 1023;
    float v = lang_in[(size_t)r * 4096 + c] + b1[c] + b2[c];
    lang_in[(size_t)r * 4096 + c] = v;
    h_att_out[idx] = v;
}

// fused 3-module e: e[item] = sum_a tanh(p + ah + b2) * aw  (one wave/item)
__global__ __launch_bounds__(256) void att_e3_kernel(
    const float* __restrict__ p0, const float* __restrict__ p1, const float* __restrict__ p2,
    const float* __restrict__ ah3,   // 3 x (128x512)
    const float* __restrict__ b0, const float* __restrict__ b1, const float* __restrict__ b2,
    const float* __restrict__ aw0, const float* __restrict__ aw1, const float* __restrict__ aw2,
    float* __restrict__ e3)          // obj @0, attr @25088, rela @50176
{
    int wid = threadIdx.x >> 6, lane = threadIdx.x & 63;
    int idx = blockIdx.x * 4 + wid;             // 0..58367
    const float* p; const float* bb; const float* aw; int S, loc, mod;
    if (idx < 25088)      { mod = 0; loc = idx;          p = p0; bb = b0; aw = aw0; S = 196; }
    else if (idx < 50176) { mod = 1; loc = idx - 25088;  p = p1; bb = b1; aw = aw1; S = 196; }
    else                  { mod = 2; loc = idx - 50176;  p = p2; bb = b2; aw = aw2; S = 64; }
    int b = loc / S;
    const float* pr = p + (size_t)loc * 512;
    const float* ab = ah3 + (size_t)mod * 65536 + (size_t)b * 512;
    float sum = 0.0f;
#pragma unroll
    for (int k = 0; k < 8; ++k) {
        int a = k * 64 + lane;
        sum += tanhf(pr[a] + ab[a] + bb[a]) * aw[a];
    }
#pragma unroll
    for (int off = 32; off; off >>= 1) sum += __shfl_down(sum, off);
    if (lane == 0) e3[idx] = sum;
}

// fused 3-module softmax (mask + renorm), in place on e3
__global__ __launch_bounds__(256) void softmax3_kernel(
    float* __restrict__ e3, const float* __restrict__ am, const float* __restrict__ rm)
{
    __shared__ float red[256];
    int mod = blockIdx.x >> 7, b = blockIdx.x & 127, tid = threadIdx.x;
    int S = (mod == 2) ? 64 : 196;
    float* e = e3 + ((mod == 0) ? 0 : (mod == 1) ? 25088 : 50176) + (size_t)b * S;
    const float* mask = ((mod == 2) ? rm : am) + (size_t)b * S;
    float v = (tid < S) ? e[tid] : -3.4e38f;
    red[tid] = v; __syncthreads();
    for (int s = 128; s; s >>= 1) { if (tid < s) red[tid] = fmaxf(red[tid], red[tid + s]); __syncthreads(); }
    float m = red[0]; __syncthreads();
    float p = (tid < S) ? __expf(v - m) : 0.0f;
    red[tid] = p; __syncthreads();
    for (int s = 128; s; s >>= 1) { if (tid < s) red[tid] += red[tid + s]; __syncthreads(); }
    float s1 = red[0]; __syncthreads();
    float w = (tid < S) ? (p / s1) * mask[tid] : 0.0f;
    red[tid] = w; __syncthreads();
    for (int s = 128; s; s >>= 1) { if (tid < s) red[tid] += red[tid + s]; __syncthreads(); }
    float s2 = red[0];
    if (tid < S) e[tid] = w / s2;
}

// fused 3-module weighted sum into lang_in cols 1024/2048/3072
__global__ __launch_bounds__(256) void wsum3_kernel(
    const float* __restrict__ e3,
    const float* __restrict__ f0, const float* __restrict__ f1, const float* __restrict__ f2,
    float* __restrict__ lang_in)
{
    int mod = blockIdx.x >> 9;
    int idx = (blockIdx.x & 511) * 256 + threadIdx.x;   // 128*1024
    int b = idx >> 10, d = idx & 1023;
    int S = (mod == 2) ? 64 : 196;
    const float* f = ((mod == 0) ? f0 : (mod == 1) ? f1 : f2) + ((size_t)b * S) * R + d;
    const float* wb = e3 + ((mod == 0) ? 0 : (mod == 1) ? 25088 : 50176) + (size_t)b * S;
    float acc = 0.0f;
    for (int s = 0; s < S; ++s) acc = fmaf(wb[s], f[(size_t)s * R], acc);
    lang_in[(size_t)b * 4096 + 1024 + mod * 1024 + d] = acc;
}

// st = sigmoid(n5_raw + b1 + b2) * tanh(c_lang)
__global__ __launch_bounds__(256) void st_kernel(
    const float* __restrict__ n5, const float* __restrict__ b1, const float* __restrict__ b2,
    const float* __restrict__ clang, float* __restrict__ st)
{
    int idx = blockIdx.x * 256 + threadIdx.x;
    int c = idx & 1023;
    st[idx] = sigf(n5[idx] + b1[c] + b2[c]) * tanhf(clang[idx]);
}

// fr = relu(fr_raw + frb); ho = tanh(ho_raw + hob)   (first/second half)
__global__ __launch_bounds__(256) void relutanh_kernel(
    float* __restrict__ fr, const float* __restrict__ frb,
    float* __restrict__ ho, const float* __restrict__ hob)
{
    int idx = blockIdx.x * 256 + threadIdx.x;   // 0..262143
    int c = idx & 1023;
    if (idx < 131072) fr[idx] = fmaxf(fr[idx] + frb[c], 0.0f);
    else { int i = idx - 131072; ho[i] = tanhf(ho[i] + hob[c]); }
}

// e_ada[b*197] = sum_r tanh(fre_raw + frb + hoe_raw + hob) * aw
__global__ __launch_bounds__(256) void ada_e0_kernel(
    const float* __restrict__ fre, const float* __restrict__ frb,
    const float* __restrict__ hoe, const float* __restrict__ hob,
    const float* __restrict__ aw, float* __restrict__ e)
{
    int wid = threadIdx.x >> 6, lane = threadIdx.x & 63;
    int b = blockIdx.x * 4 + wid;
    float sum = 0.0f;
#pragma unroll
    for (int k = 0; k < 16; ++k) {
        int r = k * 64 + lane;
        sum += tanhf(fre[(size_t)b * R + r] + frb[r] + hoe[(size_t)b * R + r] + hob[r]) * aw[r];
    }
#pragma unroll
    for (int off = 32; off; off >>= 1) sum += __shfl_down(sum, off);
    if (lane == 0) e[b * 197] = sum;
}

// softmax over 197 (no mask), in place
__global__ __launch_bounds__(256) void softmax_ada_kernel(float* __restrict__ e)
{
    __shared__ float red[256];
    int b = blockIdx.x, tid = threadIdx.x;
    float v = (tid < 197) ? e[(size_t)b * 197 + tid] : -3.4e38f;
    red[tid] = v; __syncthreads();
    for (int s = 128; s; s >>= 1) { if (tid < s) red[tid] = fmaxf(red[tid], red[tid + s]); __syncthreads(); }
    float m = red[0]; __syncthreads();
    float p = (tid < 197) ? __expf(v - m) : 0.0f;
    red[tid] = p; __syncthreads();
    for (int s = 128; s; s >>= 1) { if (tid < s) red[tid] += red[tid + s]; __syncthreads(); }
    float s1 = red[0];
    if (tid < 197) e[(size_t)b * 197 + tid] = p / s1;
}

// c_t_hat (dense): ct = beta*fr + (1-beta)*(PI[0]*fr + sum_s PI[1+s]*attf)
__global__ __launch_bounds__(256) void ct_kernel(
    const float* __restrict__ PI, const float* __restrict__ fr,
    const float* __restrict__ attf, float* __restrict__ ct)
{
    int idx = blockIdx.x * 256 + threadIdx.x;
    int b = idx >> 10, d = idx & 1023;
    float f = fr[idx];
    const float* pb = PI + b * 197;
    float acc = pb[0] * f;
    const float* af = attf + ((size_t)b * 196) * R + d;
    for (int s = 0; s < 196; ++s) acc = fmaf(pb[1 + s], af[(size_t)s * R], acc);
    float beta = pb[196];
    ct[idx] = beta * f + (1.0f - beta) * acc;
}

__global__ __launch_bounds__(256) void outbias_kernel(
    float* __restrict__ o, const float* __restrict__ bias)
{
    int idx = blockIdx.x * 256 + threadIdx.x;
    o[idx] += bias[idx & 1023];
}

extern "C" void kernel_launch(void* const* d_in, const int* in_sizes, int n_in,
                              void* d_out, int out_size, void* d_ws, size_t ws_size,
                              hipStream_t stream)
{
    const float* xt         = (const float*)d_in[0];
    const float* state_h    = (const float*)d_in[1];
    const float* state_c    = (const float*)d_in[2];
    const float* fc_feats   = (const float*)d_in[3];
    const float* att_feats  = (const float*)d_in[4];
    const float* obj_feats  = (const float*)d_in[5];
    const float* attr_feats = (const float*)d_in[6];
    const float* rela_feats = (const float*)d_in[7];
    const float* p_obj      = (const float*)d_in[8];
    const float* p_attr     = (const float*)d_in[9];
    const float* p_rela     = (const float*)d_in[10];
    const float* att_masks  = (const float*)d_in[11];
    const float* rela_masks = (const float*)d_in[12];
    const float* att_wih    = (const float*)d_in[13];
    const float* att_whh    = (const float*)d_in[14];
    const float* att_bih    = (const float*)d_in[15];
    const float* att_bhh    = (const float*)d_in[16];
    const float* lang_wih   = (const float*)d_in[17];
    const float* lang_whh   = (const float*)d_in[18];
    const float* lang_bih   = (const float*)d_in[19];
    const float* lang_bhh   = (const float*)d_in[20];
    const float* xt2_w      = (const float*)d_in[21];
    const float* xt2_b      = (const float*)d_in[22];
    const float* h_att2_w   = (const float*)d_in[23];
    const float* h_att2_b   = (const float*)d_in[24];
    const float* r_i2h_w    = (const float*)d_in[25];
    const float* r_i2h_b    = (const float*)d_in[26];
    const float* r_h2h_w    = (const float*)d_in[27];
    const float* r_h2h_b    = (const float*)d_in[28];
    const float* huu_w      = (const float*)d_in[29];
    const float* huu_b      = (const float*)d_in[30];
    const float* obj_h2att_w  = (const float*)d_in[31];
    const float* obj_h2att_b  = (const float*)d_in[32];
    const float* obj_alpha_w  = (const float*)d_in[33];
    const float* attr_h2att_w = (const float*)d_in[35];
    const float* attr_h2att_b = (const float*)d_in[36];
    const float* attr_alpha_w = (const float*)d_in[37];
    const float* rela_h2att_w = (const float*)d_in[39];
    const float* rela_h2att_b = (const float*)d_in[40];
    const float* rela_alpha_w = (const float*)d_in[41];
    const float* fr_lin_w   = (const float*)d_in[43];
    const float* fr_lin_b   = (const float*)d_in[44];
    const float* fr_emb_w   = (const float*)d_in[45];
    const float* fr_emb_b   = (const float*)d_in[46];
    const float* ho_lin_w   = (const float*)d_in[47];
    const float* ho_lin_b   = (const float*)d_in[48];
    const float* ho_emb_w   = (const float*)d_in[49];
    const float* ho_emb_b   = (const float*)d_in[50];
    const float* ada_w      = (const float*)d_in[51];
    const float* cfe_w      = (const float*)d_in[53];
    const float* cfe_b      = (const float*)d_in[54];

    float* out = (float*)d_out;
    float* wsf = (float*)d_ws;

    // ---- ws layout (floats). [0, 1926144) = atomic targets, zeroed upfront.
    float* g        = wsf + 0;         // 128x4096 (both LSTMs; self-zeroed)
    float* lang_in  = wsf + 524288;    // 128x4096 [h_att|obj|attr|rela]
    float* att_h3   = wsf + 1048576;   // 3 x 128x512
    float* n5       = wsf + 1245184;   // 128x1024
    float* fr       = wsf + 1376256;   // 128x1024
    float* fre      = wsf + 1507328;   // 128x1024
    float* ho       = wsf + 1638400;   // 128x1024
    float* hoe      = wsf + 1769472;   // 128x1024
    float* e_ada    = wsf + 1900544;   // 128x197 (pad 25600)
    const int NATOM = 1926144;
    float* att_in    = wsf + 1926144;  // 128x3072
    float* h_att_raw = wsf + 2319360;  // 128x1024
    float* e3        = wsf + 2450432;  // 25088+25088+8192 (pad 76800)
    float* st        = wsf + 2527232;  // 128x1024
    float* ct        = wsf + 2658304;  // 128x1024

    float* h_att_out  = out + 131072;
    float* h_lang_out = out + 262144;
    float* c_att_out  = out + 393216;
    float* c_lang_out = out + 524288;

    const float* prev_h = state_h + 131072;

    GJob Z = {};
    auto mk = [&](const float* A1, int lda1, int K1, const float* W1, int ldw1,
                  float* C, int ldc, int N, int Ktot, int Kchunk) {
        GJob j = Z;
        j.A1 = A1; j.lda1 = lda1; j.K1 = K1; j.K12 = Ktot; j.Ktot = Ktot;
        j.W1 = W1; j.ldw1 = ldw1;
        j.C = C; j.ldc = ldc; j.Kchunk = Kchunk; j.nb = N / 64;
        return j;
    };

    // 1. zero all atomic targets + out
    zero2_kernel<<<(NATOM + 131072) / 256, 256, 0, stream>>>(wsf, NATOM, out);

    // 2. att_in = [prev_h | fc | xt]
    concat3_kernel<<<384, 256, 0, stream>>>(prev_h, fc_feats, xt, att_in);

    // 3. att-LSTM gates: g = [att_in | h0] @ [att_wih|att_whh]^T
    {
        GJob j = mk(att_in, 3072, 3072, att_wih, 3072, g, 4096, 4096, 4096, 1024);
        j.A2 = state_h; j.lda2 = 1024; j.W2 = att_whh; j.ldw2 = 1024; j.K12 = 4096;
        gemm_sk_kernel<<<dim3(64, 4), 256, 0, stream>>>(j, Z, Z, 1);
    }
    // 4. att LSTM cell
    lstm_kernel<<<512, 256, 0, stream>>>(g, att_bih, att_bhh, state_c, h_att_raw, c_att_out);

    // 5. h_att = [xt | h_att_raw] @ [xt2|h_att2]^T  -> lang_in col 0
    {
        GJob j = mk(xt, 1024, 1024, xt2_w, 1024, lang_in, 4096, 1024, 2048, 256);
        j.A2 = h_att_raw; j.lda2 = 1024; j.W2 = h_att2_w; j.ldw2 = 1024; j.K12 = 2048;
        gemm_sk_kernel<<<dim3(16, 8), 256, 0, stream>>>(j, Z, Z, 1);
    }
    // 6. h_att bias + copy out
    hatt_epi_kernel<<<512, 256, 0, stream>>>(lang_in, xt2_b, h_att2_b, h_att_out);

    // 7. three h2att GEMMs in one launch
    {
        GJob j0 = mk(lang_in, 4096, 1024, obj_h2att_w,  1024, att_h3 + 0,      512, 512, 1024, 128);
        GJob j1 = mk(lang_in, 4096, 1024, attr_h2att_w, 1024, att_h3 + 65536,  512, 512, 1024, 128);
        GJob j2 = mk(lang_in, 4096, 1024, rela_h2att_w, 1024, att_h3 + 131072, 512, 512, 1024, 128);
        gemm_sk_kernel<<<dim3(24, 8), 256, 0, stream>>>(j0, j1, j2, 3);
    }
    // 8-10. fused e / softmax / wsum
    att_e3_kernel<<<14592, 256, 0, stream>>>(p_obj, p_attr, p_rela, att_h3,
        obj_h2att_b, attr_h2att_b, rela_h2att_b, obj_alpha_w, attr_alpha_w, rela_alpha_w, e3);
    softmax3_kernel<<<384, 256, 0, stream>>>(e3, att_masks, rela_masks);
    wsum3_kernel<<<1536, 256, 0, stream>>>(e3, obj_feats, attr_feats, rela_feats, lang_in);

    // 11. lang gates + n5 (share A = [lang_in | prev_h]) in one launch
    {
        GJob j0 = mk(lang_in, 4096, 4096, lang_wih, 4096, g, 4096, 4096, 5120, 1280);
        j0.A2 = prev_h; j0.lda2 = 1024; j0.W2 = lang_whh; j0.ldw2 = 1024; j0.K12 = 5120;
        GJob j1 = mk(lang_in, 4096, 4096, r_i2h_w, 4096, n5, 1024, 1024, 5120, 1280);
        j1.A2 = prev_h; j1.lda2 = 1024; j1.W2 = r_h2h_w; j1.ldw2 = 1024; j1.K12 = 5120;
        gemm_sk_kernel<<<dim3(80, 4), 256, 0, stream>>>(j0, j1, Z, 2);
    }
    // 12. lang LSTM cell
    lstm_kernel<<<512, 256, 0, stream>>>(g, lang_bih, lang_bhh, state_c + 131072, h_lang_out, c_lang_out);
    // 13. st
    st_kernel<<<512, 256, 0, stream>>>(n5, r_i2h_b, r_h2h_b, c_lang_out, st);

    // 14. fr + ho GEMMs in one launch
    {
        GJob j0 = mk(st, 1024, 1024, fr_lin_w, 1024, fr, 1024, 1024, 1024, 128);
        GJob j1 = mk(h_lang_out, 1024, 1024, ho_lin_w, 1024, ho, 1024, 1024, 1024, 128);
        gemm_sk_kernel<<<dim3(32, 8), 256, 0, stream>>>(j0, j1, Z, 2);
    }
    // 15. relu/tanh epilogue
    relutanh_kernel<<<1024, 256, 0, stream>>>(fr, fr_lin_b, ho, ho_lin_b);

    // 16. fre + hoe GEMMs in one launch (biases folded downstream)
    {
        GJob j0 = mk(fr, 1024, 1024, fr_emb_w, 1024, fre, 1024, 1024, 1024, 128);
        GJob j1 = mk(ho, 1024, 1024, ho_emb_w, 1024, hoe, 1024, 1024, 1024, 128);
        gemm_sk_kernel<<<dim3(32, 8), 256, 0, stream>>>(j0, j1, Z, 2);
    }
    // 17-19. adaptive attention
    ada_e0_kernel<<<32, 256, 0, stream>>>(fre, fr_emb_b, hoe, ho_emb_b, ada_w, e_ada);
    cfe_mfma_kernel<<<dim3(8, 196), 256, 0, stream>>>(p_obj, cfe_w, cfe_b, hoe, ho_emb_b, ada_w, e_ada);
    softmax_ada_kernel<<<128, 256, 0, stream>>>(e_ada);
    // 20. c_t_hat
    ct_kernel<<<512, 256, 0, stream>>>(e_ada, fr, att_feats, ct);

    // 21. output = [h_att | h_lang | c_t_hat] @ huu^T  (3-segment A, one weight)
    {
        GJob j = mk(lang_in, 4096, 1024, huu_w, 3072, out, 1024, 1024, 3072, 384);
        j.A2 = h_lang_out; j.lda2 = 1024; j.W2 = huu_w + 1024; j.ldw2 = 3072; j.K12 = 2048;
        j.A3 = ct; j.lda3 = 1024; j.W3 = huu_w + 2048; j.ldw3 = 3072;
        gemm_sk_kernel<<<dim3(16, 8), 256, 0, stream>>>(j, Z, Z, 1);
    }
    // 22. + huu_b
    outbias_kernel<<<512, 256, 0, stream>>>(out, huu_b);

    (void)in_sizes; (void)n_in; (void)out_size; (void)ws_size;
}